// Round 1
// baseline (1688.368 us; speedup 1.0000x reference)
//
#include <hip/hip_runtime.h>
#include <hip/hip_bf16.h>
#include <math.h>

#define H 512
#define NL 4
#define N2 32
#define Bsz 8
#define Lseq 4096
#define NCH 32               // chunks along L
#define LC (Lseq/NCH)        // 128 steps per chunk
#define NH64 (H/64)          // 8

typedef __attribute__((ext_vector_type(8))) short short8;   // 8 bf16
typedef __attribute__((ext_vector_type(4))) float float4v;

// ---------------- ws layout (bytes) ----------------
// 0         : xA   (B*L*H f32)            67108864
// 67108864  : P    (B*NCH*N2*2*H f32)     33554432   } region reused:
//             yo   (B*L*H f32)            67108864   } yo overlays P after pass3
// 134217728 : ybf  (B*L*H bf16)           33554432
// 167772160 : Wbf  (NL*2H*H bf16)          4194304
// 176160768 : lam  (NL*N2*2*H f32)          524288
// 176685056 : Ct                            524288
// 177209344 : lamLc                         524288
// total ~169.6 MB

// ---------- convert W to bf16 ----------
__global__ void wconv_kernel(const float* __restrict__ W, __hip_bfloat16* __restrict__ Wbf) {
    int tid = blockIdx.x * 256 + threadIdx.x;   // NL*2H*H = 4194304
    Wbf[tid] = __float2bfloat16(W[tid]);
}

// ---------- per-(layer,h,n) SSM parameters ----------
__global__ void params_kernel(const float* __restrict__ log_dt, const float* __restrict__ A_imag,
                              const float* __restrict__ log_A_real, const float* __restrict__ Cin,
                              float* __restrict__ lam, float* __restrict__ Ct, float* __restrict__ lamLc) {
    int tid = blockIdx.x * 256 + threadIdx.x;   // NL*N2*H = 65536, tid = ((layer*N2+n)*H + h)
    int h = tid % H;
    int n = (tid / H) % N2;
    int layer = tid / (H * N2);
    float dt = expf(log_dt[layer * H + h]);
    int pidx = (layer * H + h) * N2 + n;
    float Are = -expf(log_A_real[pidx]);
    float Aim = A_imag[pidx];
    float dre = Are * dt, dim = Aim * dt;
    float er = expf(dre);
    float lre = er * cosf(dim), lim = er * sinf(dim);        // lambda = exp(dA)
    float nre = lre - 1.0f, nim = lim;                        // lambda - 1
    float inv = 1.0f / (Are * Are + Aim * Aim);
    float tre = (nre * Are + nim * Aim) * inv;                // (lambda-1)/A
    float tim = (nim * Are - nre * Aim) * inv;
    float Ccre = Cin[pidx * 2], Ccim = Cin[pidx * 2 + 1];
    float ctre = 2.0f * (Ccre * tre - Ccim * tim);            // Ct = 2*C*(lambda-1)/A
    float ctim = 2.0f * (Ccre * tim + Ccim * tre);
    float erL = expf(dre * (float)LC);
    float lLre = erL * cosf(dim * (float)LC);                 // lambda^LC
    float lLim = erL * sinf(dim * (float)LC);
    int oidx = ((layer * N2 + n) * 2) * H + h;
    lam[oidx] = lre;   lam[oidx + H] = lim;
    Ct[oidx]  = ctre;  Ct[oidx + H]  = ctim;
    lamLc[oidx] = lLre; lamLc[oidx + H] = lLim;
}

// ---------- pass1: per-chunk local end state ----------
__global__ __launch_bounds__(256) void pass1_kernel(const float* __restrict__ xin,
                                                    const float* __restrict__ lam,
                                                    float* __restrict__ P, int layer) {
    int wave = threadIdx.x >> 6, lane = threadIdx.x & 63;
    int unit = blockIdx.x * 4 + wave;            // 2048 units = b(8) * ht(8) * c(32)
    int c  = unit & (NCH - 1);
    int ht = (unit >> 5) & (NH64 - 1);
    int b  = unit >> 8;
    int h  = ht * 64 + lane;
    const float* lamL = lam + layer * (N2 * 2 * H);
    float lr[N2], li[N2], sr[N2], si[N2];
#pragma unroll
    for (int n = 0; n < N2; n++) {
        lr[n] = lamL[(n * 2) * H + h];
        li[n] = lamL[(n * 2 + 1) * H + h];
        sr[n] = 0.f; si[n] = 0.f;
    }
    const float* xp = xin + ((size_t)b * Lseq + (size_t)c * LC) * H + h;
    float u = xp[0];
    for (int l = 0; l < LC; l++) {
        int lnx = (l + 1 < LC) ? (l + 1) : (LC - 1);
        float un = xp[(size_t)lnx * H];
#pragma unroll
        for (int n = 0; n < N2; n++) {
            float a  = fmaf(lr[n], sr[n], u);
            float nr = fmaf(-li[n], si[n], a);
            float ni = fmaf(lr[n], si[n], li[n] * sr[n]);
            sr[n] = nr; si[n] = ni;
        }
        u = un;
    }
    float* Pp = P + ((size_t)(b * NCH + c) * N2 * 2) * H + h;
#pragma unroll
    for (int n = 0; n < N2; n++) {
        Pp[(size_t)(n * 2) * H]     = sr[n];
        Pp[(size_t)(n * 2 + 1) * H] = si[n];
    }
}

// ---------- combine: sequential scan over chunk boundaries; P becomes entering state ----------
__global__ void combine_kernel(float* __restrict__ P, const float* __restrict__ lamLc, int layer) {
    int tid = blockIdx.x * 256 + threadIdx.x;    // B*N2*H = 131072, tid = ((b*N2+n)*H + h)
    int h = tid % H;
    int n = (tid / H) % N2;
    int b = tid / (H * N2);
    const float* lp = lamLc + layer * (N2 * 2 * H) + (n * 2) * H + h;
    float Lr = lp[0], Li = lp[H];
    float sr = 0.f, si = 0.f;
    for (int c = 0; c < NCH; c++) {
        size_t idx = ((size_t)((b * NCH + c) * N2 + n) * 2) * H + h;
        float pr = P[idx], pi = P[idx + H];
        P[idx] = sr; P[idx + H] = si;            // entering state for chunk c
        float nr = fmaf(Lr, sr, fmaf(-Li, si, pr));
        float ni = fmaf(Lr, si, fmaf(Li, sr, pi));
        sr = nr; si = ni;
    }
}

// ---------- pass3: replay chunks, emit y = gelu(conv + D*u) as bf16 ----------
__global__ __launch_bounds__(256) void pass3_kernel(const float* __restrict__ xin,
                                                    const float* __restrict__ lam,
                                                    const float* __restrict__ Ct,
                                                    const float* __restrict__ P,
                                                    const float* __restrict__ Dp,
                                                    __hip_bfloat16* __restrict__ ybf, int layer) {
    int wave = threadIdx.x >> 6, lane = threadIdx.x & 63;
    int unit = blockIdx.x * 4 + wave;
    int c  = unit & (NCH - 1);
    int ht = (unit >> 5) & (NH64 - 1);
    int b  = unit >> 8;
    int h  = ht * 64 + lane;
    const float* lamL = lam + layer * (N2 * 2 * H);
    const float* CtL  = Ct  + layer * (N2 * 2 * H);
    float lr[N2], li[N2], ctr[N2], cti[N2], sr[N2], si[N2];
    const float* Pp = P + ((size_t)(b * NCH + c) * N2 * 2) * H + h;
#pragma unroll
    for (int n = 0; n < N2; n++) {
        lr[n]  = lamL[(n * 2) * H + h];
        li[n]  = lamL[(n * 2 + 1) * H + h];
        ctr[n] = CtL[(n * 2) * H + h];
        cti[n] = CtL[(n * 2 + 1) * H + h];
        sr[n]  = Pp[(size_t)(n * 2) * H];
        si[n]  = Pp[(size_t)(n * 2 + 1) * H];
    }
    float Dh = Dp[layer * H + h];
    const float* xp = xin + ((size_t)b * Lseq + (size_t)c * LC) * H + h;
    __hip_bfloat16* yp = ybf + ((size_t)b * Lseq + (size_t)c * LC) * H + h;
    float u = xp[0];
    for (int l = 0; l < LC; l++) {
        int lnx = (l + 1 < LC) ? (l + 1) : (LC - 1);
        float un = xp[(size_t)lnx * H];
        float ya0 = 0.f, ya1 = 0.f, ya2 = 0.f, ya3 = 0.f;
#pragma unroll
        for (int n = 0; n < N2; n += 4) {
#pragma unroll
            for (int q = 0; q < 4; q++) {
                int m = n + q;
                float a  = fmaf(lr[m], sr[m], u);
                float nr = fmaf(-li[m], si[m], a);
                float ni = fmaf(lr[m], si[m], li[m] * sr[m]);
                sr[m] = nr; si[m] = ni;
                float* yq = (q == 0) ? &ya0 : (q == 1) ? &ya1 : (q == 2) ? &ya2 : &ya3;
                *yq = fmaf(ctr[m], nr, *yq);
                *yq = fmaf(-cti[m], ni, *yq);
            }
        }
        float y = (ya0 + ya1) + (ya2 + ya3) + Dh * u;
        float g = 0.5f * y * (1.0f + erff(y * 0.70710678118654752f));
        yp[(size_t)l * H] = __float2bfloat16(g);
        u = un;
    }
}

// ---------- fused 1x1 conv (bf16 MFMA) + bias + GLU ----------
__global__ __launch_bounds__(256) void gemm_glu_kernel(const __hip_bfloat16* __restrict__ ybf,
                                                       const __hip_bfloat16* __restrict__ Wbf,
                                                       const float* __restrict__ bias,
                                                       float* __restrict__ yo, int layer) {
    int wave = threadIdx.x >> 6, lane = threadIdx.x & 63;
    int wr = wave >> 1, wc = wave & 1;
    int bz = blockIdx.z;
    int m0 = blockIdx.x * 64 + wr * 32;          // l tile
    int o0 = blockIdx.y * 64 + wc * 32;          // output-channel tile (a half)
    int r16 = lane & 15, quad = lane >> 4;
    const __hip_bfloat16* Wl = Wbf + (size_t)layer * 2 * H * H;
    float4v acc_a[2][2] = {}, acc_g[2][2] = {};
    for (int k0 = 0; k0 < H; k0 += 32) {
        int ko = k0 + quad * 8;
        short8 afr[2], bfa[2], bfg[2];
#pragma unroll
        for (int mi = 0; mi < 2; mi++)
            afr[mi] = *reinterpret_cast<const short8*>(ybf + ((size_t)bz * Lseq + m0 + mi * 16 + r16) * H + ko);
#pragma unroll
        for (int ni = 0; ni < 2; ni++) {
            bfa[ni] = *reinterpret_cast<const short8*>(Wl + (size_t)(o0 + ni * 16 + r16) * H + ko);
            bfg[ni] = *reinterpret_cast<const short8*>(Wl + (size_t)(H + o0 + ni * 16 + r16) * H + ko);
        }
#pragma unroll
        for (int mi = 0; mi < 2; mi++)
#pragma unroll
            for (int ni = 0; ni < 2; ni++) {
                acc_a[mi][ni] = __builtin_amdgcn_mfma_f32_16x16x32_bf16(afr[mi], bfa[ni], acc_a[mi][ni], 0, 0, 0);
                acc_g[mi][ni] = __builtin_amdgcn_mfma_f32_16x16x32_bf16(afr[mi], bfg[ni], acc_g[mi][ni], 0, 0, 0);
            }
    }
    const float* bl = bias + layer * 2 * H;
#pragma unroll
    for (int ni = 0; ni < 2; ni++) {
        int o = o0 + ni * 16 + r16;
        float ba = bl[o], bg = bl[H + o];
#pragma unroll
        for (int mi = 0; mi < 2; mi++)
#pragma unroll
            for (int r = 0; r < 4; r++) {
                int l = m0 + mi * 16 + quad * 4 + r;         // C/D: col=lane&15, row=quad*4+reg
                float av = acc_a[mi][ni][r] + ba;
                float gv = acc_g[mi][ni][r] + bg;
                float val = av * (1.0f / (1.0f + expf(-gv)));
                yo[((size_t)bz * Lseq + l) * H + o] = val;
            }
    }
}

// ---------- residual + LayerNorm ----------
__global__ __launch_bounds__(256) void ln_kernel(const float* __restrict__ yo, const float* __restrict__ xin,
                                                 const float* __restrict__ gamma, const float* __restrict__ beta,
                                                 float* __restrict__ xout, int layer) {
    int wave = threadIdx.x >> 6, lane = threadIdx.x & 63;
    size_t row = (size_t)blockIdx.x * 4 + wave;   // B*L rows
    const float* yp = yo + row * H;
    const float* xp = xin + row * H;
    float v[8];
    float s = 0.f, s2 = 0.f;
#pragma unroll
    for (int i = 0; i < 8; i++) {
        int hh = lane * 8 + i;
        float t = yp[hh] + xp[hh];
        v[i] = t; s += t; s2 = fmaf(t, t, s2);
    }
#pragma unroll
    for (int off = 32; off; off >>= 1) {
        s  += __shfl_xor(s, off);
        s2 += __shfl_xor(s2, off);
    }
    float mu = s * (1.0f / H);
    float var = s2 * (1.0f / H) - mu * mu;
    float inv = rsqrtf(var + 1e-5f);
    const float* gl = gamma + layer * H;
    const float* bl = beta + layer * H;
#pragma unroll
    for (int i = 0; i < 8; i++) {
        int hh = lane * 8 + i;
        xout[row * H + hh] = (v[i] - mu) * inv * gl[hh] + bl[hh];
    }
}

extern "C" void kernel_launch(void* const* d_in, const int* in_sizes, int n_in,
                              void* d_out, int out_size, void* d_ws, size_t ws_size,
                              hipStream_t stream) {
    const float* x          = (const float*)d_in[0];
    const float* log_dt     = (const float*)d_in[1];
    const float* A_imag     = (const float*)d_in[2];
    const float* log_A_real = (const float*)d_in[3];
    const float* C          = (const float*)d_in[4];
    const float* D          = (const float*)d_in[5];
    const float* W          = (const float*)d_in[6];
    const float* bias       = (const float*)d_in[7];
    const float* gamma      = (const float*)d_in[8];
    const float* beta       = (const float*)d_in[9];

    char* ws = (char*)d_ws;
    float* xA            = (float*)(ws + 0);
    float* P             = (float*)(ws + 67108864);   // overlaid by yo after pass3
    float* yo            = (float*)(ws + 67108864);
    __hip_bfloat16* ybf  = (__hip_bfloat16*)(ws + 134217728);
    __hip_bfloat16* Wbf  = (__hip_bfloat16*)(ws + 167772160);
    float* lam           = (float*)(ws + 176160768);
    float* Ct            = (float*)(ws + 176685056);
    float* lamLc         = (float*)(ws + 177209344);
    float* xout_final    = (float*)d_out;

    wconv_kernel<<<NL * 2 * H * H / 256, 256, 0, stream>>>(W, Wbf);
    params_kernel<<<NL * N2 * H / 256, 256, 0, stream>>>(log_dt, A_imag, log_A_real, C, lam, Ct, lamLc);

    const float* xi = x;
    float* bufs[NL] = { xA, xout_final, xA, xout_final };
    for (int layer = 0; layer < NL; ++layer) {
        float* xo = bufs[layer];
        pass1_kernel<<<512, 256, 0, stream>>>(xi, lam, P, layer);
        combine_kernel<<<Bsz * N2 * H / 256, 256, 0, stream>>>(P, lamLc, layer);
        pass3_kernel<<<512, 256, 0, stream>>>(xi, lam, Ct, P, D, ybf, layer);
        gemm_glu_kernel<<<dim3(Lseq / 64, H / 64, Bsz), 256, 0, stream>>>(ybf, Wbf, bias, yo, layer);
        ln_kernel<<<Bsz * Lseq / 4, 256, 0, stream>>>(yo, xi, gamma, beta, xo, layer);
        xi = xo;
    }
}

// Round 2
// 1241.851 us; speedup vs baseline: 1.3596x; 1.3596x over previous
//
#include <hip/hip_runtime.h>
#include <hip/hip_bf16.h>
#include <math.h>

#define H 512
#define NL 4
#define N2 32
#define Bsz 8
#define Lseq 4096
#define NCH 32               // chunks along L
#define LC (Lseq/NCH)        // 128 steps per chunk
#define NH64 (H/64)          // 8

typedef __attribute__((ext_vector_type(8))) short short8;   // 8 bf16
typedef __attribute__((ext_vector_type(4))) float float4v;

// ---------------- ws layout (bytes) ----------------
// 0         : xA   (B*L*H f32)            67108864
// 67108864  : P    (B*NCH*N2*2*H f32)     33554432   } region reused:
//             yo   (B*L*H f32)            67108864   } yo overlays P after pass3
// 134217728 : ybf  (B*L*H bf16)           33554432
// 167772160 : Wbf  (NL*2H*H bf16)          4194304
// 176160768 : lam  (NL*N2*2*H f32)          524288
// 176685056 : Ct                            524288
// 177209344 : lamLc                         524288

// async global->LDS copy, 16 B per lane (wave-uniform LDS base + lane*16)
__device__ __forceinline__ void async_copy16(const __hip_bfloat16* g, __hip_bfloat16* l) {
    __builtin_amdgcn_global_load_lds(
        (const __attribute__((address_space(1))) void*)g,
        (__attribute__((address_space(3))) void*)l,
        16, 0, 0);
}

// ---------- convert W to bf16 ----------
__global__ void wconv_kernel(const float* __restrict__ W, __hip_bfloat16* __restrict__ Wbf) {
    int tid = blockIdx.x * 256 + threadIdx.x;   // NL*2H*H = 4194304
    Wbf[tid] = __float2bfloat16(W[tid]);
}

// ---------- per-(layer,h,n) SSM parameters ----------
__global__ void params_kernel(const float* __restrict__ log_dt, const float* __restrict__ A_imag,
                              const float* __restrict__ log_A_real, const float* __restrict__ Cin,
                              float* __restrict__ lam, float* __restrict__ Ct, float* __restrict__ lamLc) {
    int tid = blockIdx.x * 256 + threadIdx.x;   // NL*N2*H = 65536, tid = ((layer*N2+n)*H + h)
    int h = tid % H;
    int n = (tid / H) % N2;
    int layer = tid / (H * N2);
    float dt = expf(log_dt[layer * H + h]);
    int pidx = (layer * H + h) * N2 + n;
    float Are = -expf(log_A_real[pidx]);
    float Aim = A_imag[pidx];
    float dre = Are * dt, dim = Aim * dt;
    float er = expf(dre);
    float lre = er * cosf(dim), lim = er * sinf(dim);        // lambda = exp(dA)
    float nre = lre - 1.0f, nim = lim;                        // lambda - 1
    float inv = 1.0f / (Are * Are + Aim * Aim);
    float tre = (nre * Are + nim * Aim) * inv;                // (lambda-1)/A
    float tim = (nim * Are - nre * Aim) * inv;
    float Ccre = Cin[pidx * 2], Ccim = Cin[pidx * 2 + 1];
    float ctre = 2.0f * (Ccre * tre - Ccim * tim);            // Ct = 2*C*(lambda-1)/A
    float ctim = 2.0f * (Ccre * tim + Ccim * tre);
    float erL = expf(dre * (float)LC);
    float lLre = erL * cosf(dim * (float)LC);                 // lambda^LC
    float lLim = erL * sinf(dim * (float)LC);
    int oidx = ((layer * N2 + n) * 2) * H + h;
    lam[oidx] = lre;   lam[oidx + H] = lim;
    Ct[oidx]  = ctre;  Ct[oidx + H]  = ctim;
    lamLc[oidx] = lLre; lamLc[oidx + H] = lLim;
}

// ---------- pass1: per-chunk local end state ----------
__global__ __launch_bounds__(256) void pass1_kernel(const float* __restrict__ xin,
                                                    const float* __restrict__ lam,
                                                    float* __restrict__ P, int layer) {
    int wave = threadIdx.x >> 6, lane = threadIdx.x & 63;
    int unit = blockIdx.x * 4 + wave;            // 2048 units = b(8) * ht(8) * c(32)
    int c  = unit & (NCH - 1);
    int ht = (unit >> 5) & (NH64 - 1);
    int b  = unit >> 8;
    int h  = ht * 64 + lane;
    const float* lamL = lam + layer * (N2 * 2 * H);
    float lr[N2], li[N2], sr[N2], si[N2];
#pragma unroll
    for (int n = 0; n < N2; n++) {
        lr[n] = lamL[(n * 2) * H + h];
        li[n] = lamL[(n * 2 + 1) * H + h];
        sr[n] = 0.f; si[n] = 0.f;
    }
    const float* xp = xin + ((size_t)b * Lseq + (size_t)c * LC) * H + h;
    float u = xp[0];
    for (int l = 0; l < LC; l++) {
        int lnx = (l + 1 < LC) ? (l + 1) : (LC - 1);
        float un = xp[(size_t)lnx * H];
#pragma unroll
        for (int n = 0; n < N2; n++) {
            float a  = fmaf(lr[n], sr[n], u);
            float nr = fmaf(-li[n], si[n], a);
            float ni = fmaf(lr[n], si[n], li[n] * sr[n]);
            sr[n] = nr; si[n] = ni;
        }
        u = un;
    }
    float* Pp = P + ((size_t)(b * NCH + c) * N2 * 2) * H + h;
#pragma unroll
    for (int n = 0; n < N2; n++) {
        Pp[(size_t)(n * 2) * H]     = sr[n];
        Pp[(size_t)(n * 2 + 1) * H] = si[n];
    }
}

// ---------- combine: sequential scan over chunk boundaries; P becomes entering state ----------
__global__ void combine_kernel(float* __restrict__ P, const float* __restrict__ lamLc, int layer) {
    int tid = blockIdx.x * 256 + threadIdx.x;    // B*N2*H = 131072, tid = ((b*N2+n)*H + h)
    int h = tid % H;
    int n = (tid / H) % N2;
    int b = tid / (H * N2);
    const float* lp = lamLc + layer * (N2 * 2 * H) + (n * 2) * H + h;
    float Lr = lp[0], Li = lp[H];
    float sr = 0.f, si = 0.f;
    for (int c = 0; c < NCH; c++) {
        size_t idx = ((size_t)((b * NCH + c) * N2 + n) * 2) * H + h;
        float pr = P[idx], pi = P[idx + H];
        P[idx] = sr; P[idx + H] = si;            // entering state for chunk c
        float nr = fmaf(Lr, sr, fmaf(-Li, si, pr));
        float ni = fmaf(Lr, si, fmaf(Li, sr, pi));
        sr = nr; si = ni;
    }
}

// ---------- pass3: replay chunks, emit y = gelu(conv + D*u) as bf16 ----------
__global__ __launch_bounds__(256) void pass3_kernel(const float* __restrict__ xin,
                                                    const float* __restrict__ lam,
                                                    const float* __restrict__ Ct,
                                                    const float* __restrict__ P,
                                                    const float* __restrict__ Dp,
                                                    __hip_bfloat16* __restrict__ ybf, int layer) {
    int wave = threadIdx.x >> 6, lane = threadIdx.x & 63;
    int unit = blockIdx.x * 4 + wave;
    int c  = unit & (NCH - 1);
    int ht = (unit >> 5) & (NH64 - 1);
    int b  = unit >> 8;
    int h  = ht * 64 + lane;
    const float* lamL = lam + layer * (N2 * 2 * H);
    const float* CtL  = Ct  + layer * (N2 * 2 * H);
    float lr[N2], li[N2], ctr[N2], cti[N2], sr[N2], si[N2];
    const float* Pp = P + ((size_t)(b * NCH + c) * N2 * 2) * H + h;
#pragma unroll
    for (int n = 0; n < N2; n++) {
        lr[n]  = lamL[(n * 2) * H + h];
        li[n]  = lamL[(n * 2 + 1) * H + h];
        ctr[n] = CtL[(n * 2) * H + h];
        cti[n] = CtL[(n * 2 + 1) * H + h];
        sr[n]  = Pp[(size_t)(n * 2) * H];
        si[n]  = Pp[(size_t)(n * 2 + 1) * H];
    }
    float Dh = Dp[layer * H + h];
    const float* xp = xin + ((size_t)b * Lseq + (size_t)c * LC) * H + h;
    __hip_bfloat16* yp = ybf + ((size_t)b * Lseq + (size_t)c * LC) * H + h;
    float u = xp[0];
    for (int l = 0; l < LC; l++) {
        int lnx = (l + 1 < LC) ? (l + 1) : (LC - 1);
        float un = xp[(size_t)lnx * H];
        float ya0 = 0.f, ya1 = 0.f, ya2 = 0.f, ya3 = 0.f;
#pragma unroll
        for (int n = 0; n < N2; n += 4) {
#pragma unroll
            for (int q = 0; q < 4; q++) {
                int m = n + q;
                float a  = fmaf(lr[m], sr[m], u);
                float nr = fmaf(-li[m], si[m], a);
                float ni = fmaf(lr[m], si[m], li[m] * sr[m]);
                sr[m] = nr; si[m] = ni;
                float* yq = (q == 0) ? &ya0 : (q == 1) ? &ya1 : (q == 2) ? &ya2 : &ya3;
                *yq = fmaf(ctr[m], nr, *yq);
                *yq = fmaf(-cti[m], ni, *yq);
            }
        }
        float y = (ya0 + ya1) + (ya2 + ya3) + Dh * u;
        float g = 0.5f * y * (1.0f + erff(y * 0.70710678118654752f));
        yp[(size_t)l * H] = __float2bfloat16(g);
        u = un;
    }
}

// ---------- fused 1x1 conv: m97-style LDS-tiled bf16 MFMA GEMM + bias + GLU ----------
// Tile: BM=128 rows (l), BN=64 channel-pairs (a at o, g at o+512), BK=32.
// LDS: As[128][32], Bs[128][32] (rows 0..63 = a-channels, 64..127 = g-channels).
// Waves 2x2: wr = m-half (64 rows), wc = channel-half (32 channels).
__global__ __launch_bounds__(256) void gemm_glu_kernel(const __hip_bfloat16* __restrict__ ybf,
                                                       const __hip_bfloat16* __restrict__ Wbf,
                                                       const float* __restrict__ bias,
                                                       float* __restrict__ yo, int layer) {
    __shared__ __hip_bfloat16 As[128 * 32];
    __shared__ __hip_bfloat16 Bs[128 * 32];
    int tid = threadIdx.x;
    int wave = tid >> 6, lane = tid & 63;
    int wr = wave >> 1, wc = wave & 1;
    int r16 = lane & 15, quad = lane >> 4;
    int m0 = blockIdx.x * 128;                   // over B*L = 32768 rows
    int o0 = blockIdx.y * 64;                    // a-channel base (g = +512)
    const __hip_bfloat16* Wl = Wbf + (size_t)layer * 2 * H * H;

    // staging: each wave stages 16 rows per call (lane -> row lane>>2, col (lane&3)*8)
    int srow = lane >> 2;
    int scol = (lane & 3) * 8;
    const __hip_bfloat16* aSrc0 = ybf + ((size_t)(m0 + wave * 16 + srow)) * H + scol;
    const __hip_bfloat16* aSrc1 = aSrc0 + (size_t)64 * H;
    const __hip_bfloat16* bSrcA = Wl + ((size_t)(o0 + wave * 16 + srow)) * H + scol;
    const __hip_bfloat16* bSrcG = bSrcA + (size_t)512 * H;
    __hip_bfloat16* aDst0 = As + (wave * 16) * 32;
    __hip_bfloat16* aDst1 = As + (64 + wave * 16) * 32;
    __hip_bfloat16* bDstA = Bs + (wave * 16) * 32;
    __hip_bfloat16* bDstG = Bs + (64 + wave * 16) * 32;

    float4v acc_a[4][2] = {}, acc_g[4][2] = {};

    for (int k0 = 0; k0 < H; k0 += 32) {
        __syncthreads();                          // previous iter's ds_reads done
        async_copy16(aSrc0, aDst0);
        async_copy16(aSrc1, aDst1);
        async_copy16(bSrcA, bDstA);
        async_copy16(bSrcG, bDstG);
        aSrc0 += 32; aSrc1 += 32; bSrcA += 32; bSrcG += 32;
        __syncthreads();                          // drains vmcnt -> LDS tile visible

        short8 af[4], ba[2], bg[2];
#pragma unroll
        for (int mi = 0; mi < 4; mi++)
            af[mi] = *reinterpret_cast<const short8*>(As + (wr * 64 + mi * 16 + r16) * 32 + quad * 8);
#pragma unroll
        for (int ni = 0; ni < 2; ni++) {
            ba[ni] = *reinterpret_cast<const short8*>(Bs + (wc * 32 + ni * 16 + r16) * 32 + quad * 8);
            bg[ni] = *reinterpret_cast<const short8*>(Bs + (64 + wc * 32 + ni * 16 + r16) * 32 + quad * 8);
        }
#pragma unroll
        for (int mi = 0; mi < 4; mi++)
#pragma unroll
            for (int ni = 0; ni < 2; ni++) {
                acc_a[mi][ni] = __builtin_amdgcn_mfma_f32_16x16x32_bf16(af[mi], ba[ni], acc_a[mi][ni], 0, 0, 0);
                acc_g[mi][ni] = __builtin_amdgcn_mfma_f32_16x16x32_bf16(af[mi], bg[ni], acc_g[mi][ni], 0, 0, 0);
            }
    }

    const float* bl = bias + layer * 2 * H;
#pragma unroll
    for (int ni = 0; ni < 2; ni++) {
        int o = o0 + wc * 32 + ni * 16 + r16;
        float ba_ = bl[o], bg_ = bl[H + o];
#pragma unroll
        for (int mi = 0; mi < 4; mi++)
#pragma unroll
            for (int r = 0; r < 4; r++) {
                int l = m0 + wr * 64 + mi * 16 + quad * 4 + r;   // C/D: col=lane&15, row=quad*4+reg
                float av = acc_a[mi][ni][r] + ba_;
                float gv = acc_g[mi][ni][r] + bg_;
                yo[(size_t)l * H + o] = av * (1.0f / (1.0f + expf(-gv)));
            }
    }
}

// ---------- residual + LayerNorm ----------
__global__ __launch_bounds__(256) void ln_kernel(const float* __restrict__ yo, const float* __restrict__ xin,
                                                 const float* __restrict__ gamma, const float* __restrict__ beta,
                                                 float* __restrict__ xout, int layer) {
    int wave = threadIdx.x >> 6, lane = threadIdx.x & 63;
    size_t row = (size_t)blockIdx.x * 4 + wave;   // B*L rows
    const float* yp = yo + row * H;
    const float* xp = xin + row * H;
    float v[8];
    float s = 0.f, s2 = 0.f;
#pragma unroll
    for (int i = 0; i < 8; i++) {
        int hh = lane * 8 + i;
        float t = yp[hh] + xp[hh];
        v[i] = t; s += t; s2 = fmaf(t, t, s2);
    }
#pragma unroll
    for (int off = 32; off; off >>= 1) {
        s  += __shfl_xor(s, off);
        s2 += __shfl_xor(s2, off);
    }
    float mu = s * (1.0f / H);
    float var = s2 * (1.0f / H) - mu * mu;
    float inv = rsqrtf(var + 1e-5f);
    const float* gl = gamma + layer * H;
    const float* bl = beta + layer * H;
#pragma unroll
    for (int i = 0; i < 8; i++) {
        int hh = lane * 8 + i;
        xout[row * H + hh] = (v[i] - mu) * inv * gl[hh] + bl[hh];
    }
}

extern "C" void kernel_launch(void* const* d_in, const int* in_sizes, int n_in,
                              void* d_out, int out_size, void* d_ws, size_t ws_size,
                              hipStream_t stream) {
    const float* x          = (const float*)d_in[0];
    const float* log_dt     = (const float*)d_in[1];
    const float* A_imag     = (const float*)d_in[2];
    const float* log_A_real = (const float*)d_in[3];
    const float* C          = (const float*)d_in[4];
    const float* D          = (const float*)d_in[5];
    const float* W          = (const float*)d_in[6];
    const float* bias       = (const float*)d_in[7];
    const float* gamma      = (const float*)d_in[8];
    const float* beta       = (const float*)d_in[9];

    char* ws = (char*)d_ws;
    float* xA            = (float*)(ws + 0);
    float* P             = (float*)(ws + 67108864);   // overlaid by yo after pass3
    float* yo            = (float*)(ws + 67108864);
    __hip_bfloat16* ybf  = (__hip_bfloat16*)(ws + 134217728);
    __hip_bfloat16* Wbf  = (__hip_bfloat16*)(ws + 167772160);
    float* lam           = (float*)(ws + 176160768);
    float* Ct            = (float*)(ws + 176685056);
    float* lamLc         = (float*)(ws + 177209344);
    float* xout_final    = (float*)d_out;

    wconv_kernel<<<NL * 2 * H * H / 256, 256, 0, stream>>>(W, Wbf);
    params_kernel<<<NL * N2 * H / 256, 256, 0, stream>>>(log_dt, A_imag, log_A_real, C, lam, Ct, lamLc);

    const float* xi = x;
    float* bufs[NL] = { xA, xout_final, xA, xout_final };
    for (int layer = 0; layer < NL; ++layer) {
        float* xo = bufs[layer];
        pass1_kernel<<<512, 256, 0, stream>>>(xi, lam, P, layer);
        combine_kernel<<<Bsz * N2 * H / 256, 256, 0, stream>>>(P, lamLc, layer);
        pass3_kernel<<<512, 256, 0, stream>>>(xi, lam, Ct, P, D, ybf, layer);
        gemm_glu_kernel<<<dim3((Bsz * Lseq) / 128, H / 64), 256, 0, stream>>>(ybf, Wbf, bias, yo, layer);
        ln_kernel<<<Bsz * Lseq / 4, 256, 0, stream>>>(yo, xi, gamma, beta, xo, layer);
        xi = xo;
    }
}

// Round 3
// 922.957 us; speedup vs baseline: 1.8293x; 1.3455x over previous
//
#include <hip/hip_runtime.h>
#include <hip/hip_bf16.h>
#include <math.h>

#define H 512
#define NL 4
#define N2 32
#define Bsz 8
#define Lseq 4096
#define BT (Bsz*Lseq)        // 32768 total positions
#define LC2 64               // chunk length
#define NCC (BT/LC2)         // 512 chunks total
#define CPB (Lseq/LC2)       // 64 chunks per batch element

typedef __attribute__((ext_vector_type(8))) short short8;   // 8 bf16
typedef __attribute__((ext_vector_type(4))) float float4v;

// ---------------- ws layout (bytes), total 177,471,488 <= 177.7MB proven ----
// 0         : xA   (fp32 BT*H)                 67108864
// 67108864  : Sloc (bf16 H*NCC*64)             33554432   (local then entering states)
// 100663296 : u_t  (bf16 H*BT) / ybf overlay   33554432
// 134217728 : y_t  (bf16 H*BT) / yo overlay    33554432
// 167772160 : Wbf  (bf16 NL*2H*H)               4194304
// 171966464 : WV   (bf16 H*64*64, Wstate->V)    4194304
// 176160768 : kmat (bf16 NL*H*64)                262144
// 176422912 : dA   (fp32 NL*N2*2*H)              524288
// 176947200 : Ct   (fp32 NL*N2*2*H)              524288

__device__ __forceinline__ float bf2f(unsigned short u) {
    union { unsigned int i; float f; } x; x.i = ((unsigned int)u) << 16; return x.f;
}
__device__ __forceinline__ unsigned short f2bf(float f) {
    union { float f; unsigned int i; } x; x.f = f;
    unsigned int u = x.i + 0x7fff + ((x.i >> 16) & 1);
    return (unsigned short)(u >> 16);
}
__device__ __forceinline__ uint2 pack4bf(float a, float b, float c, float d) {
    uint2 r;
    r.x = (unsigned)f2bf(a) | ((unsigned)f2bf(b) << 16);
    r.y = (unsigned)f2bf(c) | ((unsigned)f2bf(d) << 16);
    return r;
}
__device__ __forceinline__ void async_copy16(const void* g, void* l) {
    __builtin_amdgcn_global_load_lds(
        (const __attribute__((address_space(1))) void*)g,
        (__attribute__((address_space(3))) void*)l, 16, 0, 0);
}

// ---------- convert W to bf16 ----------
__global__ void wconv_kernel(const float* __restrict__ W, unsigned short* __restrict__ Wbf) {
    int tid = blockIdx.x * 256 + threadIdx.x;
    Wbf[tid] = f2bf(W[tid]);
}

// ---------- per-(layer,n,h): dA = log(lambda), Ct = 2C(lambda-1)/A ----------
__global__ void params_kernel(const float* __restrict__ log_dt, const float* __restrict__ A_imag,
                              const float* __restrict__ log_A_real, const float* __restrict__ Cin,
                              float* __restrict__ dA, float* __restrict__ Ct) {
    int tid = blockIdx.x * 256 + threadIdx.x;   // ((layer*N2+n)*H + h)
    int h = tid % H;
    int n = (tid / H) % N2;
    int layer = tid / (H * N2);
    float dt = expf(log_dt[layer * H + h]);
    int pidx = (layer * H + h) * N2 + n;
    float Are = -expf(log_A_real[pidx]);
    float Aim = A_imag[pidx];
    float dre = Are * dt, dim = Aim * dt;
    float er = expf(dre);
    float lre = er * cosf(dim), lim = er * sinf(dim);
    float nre = lre - 1.0f, nim = lim;
    float inv = 1.0f / (Are * Are + Aim * Aim);
    float tre = (nre * Are + nim * Aim) * inv;
    float tim = (nim * Are - nre * Aim) * inv;
    float Ccre = Cin[pidx * 2], Ccim = Cin[pidx * 2 + 1];
    int oidx = ((layer * N2 + n) * 2) * H + h;
    dA[oidx] = dre;  dA[oidx + H] = dim;
    Ct[oidx] = 2.0f * (Ccre * tre - Ccim * tim);
    Ct[oidx + H] = 2.0f * (Ccre * tim + Ccim * tre);
}

// ---------- kernels k[d] = Re sum_n Ct_n lambda_n^d, all layers ----------
__global__ void kergen_k_kernel(const float* __restrict__ dA, const float* __restrict__ Ct,
                                unsigned short* __restrict__ kmat) {
    int t = blockIdx.x * 256 + threadIdx.x;     // (layer*H + h)*64 + d
    int d = t & 63;
    int h = (t >> 6) & (H - 1);
    int layer = t >> 15;
    float fd = (float)d;
    float sum = 0.f;
    for (int n = 0; n < N2; n++) {
        int base = ((layer * N2 + n) * 2) * H + h;
        float dre = dA[base], dim = dA[base + H];
        float Ctr = Ct[base], Cti = Ct[base + H];
        float e = expf(dre * fd);
        sum += Ctr * e * cosf(dim * fd) - Cti * e * sinf(dim * fd);
    }
    kmat[t] = f2bf(sum);
}

// ---------- Wstate[h][r][j]: r=2n -> Re(l^(63-j)), r=2n+1 -> Im ----------
__global__ void kergenW_kernel(const float* __restrict__ dA, unsigned short* __restrict__ Wst, int layer) {
    int t = blockIdx.x * 256 + threadIdx.x;     // (h*64 + r)*64 + j
    int j = t & 63;
    int r = (t >> 6) & 63;
    int h = t >> 12;
    int n = r >> 1;
    int base = ((layer * N2 + n) * 2) * H + h;
    float dre = dA[base], dim = dA[base + H];
    float p = (float)(63 - j);
    float e = expf(dre * p);
    Wst[t] = f2bf((r & 1) ? e * sinf(dim * p) : e * cosf(dim * p));
}

// ---------- V[h][l][c2]: c2=2n -> Re(Ct l^(l+1)), c2=2n+1 -> -Im ----------
__global__ void kergenV_kernel(const float* __restrict__ dA, const float* __restrict__ Ct,
                               unsigned short* __restrict__ Vl, int layer) {
    int t = blockIdx.x * 256 + threadIdx.x;     // (h*64 + l)*64 + c2
    int c2 = t & 63;
    int l = (t >> 6) & 63;
    int h = t >> 12;
    int n = c2 >> 1;
    int base = ((layer * N2 + n) * 2) * H + h;
    float dre = dA[base], dim = dA[base + H];
    float Ctr = Ct[base], Cti = Ct[base + H];
    float q = (float)(l + 1);
    float e = expf(dre * q);
    float ar = e * cosf(dim * q), ai = e * sinf(dim * q);
    float vre = Ctr * ar - Cti * ai;
    float vim = Ctr * ai + Cti * ar;
    Vl[t] = f2bf((c2 & 1) ? -vim : vre);
}

// ---------- transpose x (BT,H fp32) -> u_t (H,BT bf16) ----------
__global__ __launch_bounds__(256) void transpose1_kernel(const float* __restrict__ xi,
                                                         unsigned short* __restrict__ ut) {
    __shared__ float tile[64][68];
    int bx = blockIdx.x;
    int pt = bx & 511, ht = bx >> 9;
    int p0 = pt * 64, h0 = ht * 64;
    int t = threadIdx.x;
    int jr = t & 15, ib = t >> 4;
#pragma unroll
    for (int pass = 0; pass < 4; pass++) {
        int i = ib + pass * 16;
        float4 v = *(const float4*)(xi + (size_t)(p0 + i) * H + h0 + jr * 4);
        tile[i][jr * 4 + 0] = v.x; tile[i][jr * 4 + 1] = v.y;
        tile[i][jr * 4 + 2] = v.z; tile[i][jr * 4 + 3] = v.w;
    }
    __syncthreads();
#pragma unroll
    for (int pass = 0; pass < 4; pass++) {
        int i2 = ib + pass * 16;
        int j2 = jr * 4;
        uint2 pk = pack4bf(tile[j2][i2], tile[j2 + 1][i2], tile[j2 + 2][i2], tile[j2 + 3][i2]);
        *(uint2*)(ut + (size_t)(h0 + i2) * BT + p0 + j2) = pk;
    }
}

// ---------- local chunk states: Sloc[h][cc][r] = sum_j Wst[r][j] u[cc*64+j] ----------
__global__ __launch_bounds__(256) void states_kernel(const unsigned short* __restrict__ ut,
                                                     const unsigned short* __restrict__ Wst,
                                                     unsigned short* __restrict__ Sloc) {
    int h = blockIdx.x;
    int wave = threadIdx.x >> 6, lane = threadIdx.x & 63;
    int r16 = lane & 15, quad = lane >> 4;
    const unsigned short* uh = ut + (size_t)h * BT;
    const unsigned short* wh = Wst + (size_t)h * 64 * 64;
    unsigned short* sh = Sloc + (size_t)h * NCC * 64;
    for (int nt = 0; nt < 8; nt++) {
        int cc0 = wave * 128 + nt * 16;
        float4v acc[4] = {};
#pragma unroll
        for (int k0 = 0; k0 < 64; k0 += 32) {
            short8 bf = *reinterpret_cast<const short8*>(uh + (size_t)(cc0 + r16) * 64 + k0 + quad * 8);
#pragma unroll
            for (int mt = 0; mt < 4; mt++) {
                short8 af = *reinterpret_cast<const short8*>(wh + (mt * 16 + r16) * 64 + k0 + quad * 8);
                acc[mt] = __builtin_amdgcn_mfma_f32_16x16x32_bf16(af, bf, acc[mt], 0, 0, 0);
            }
        }
        int cc = cc0 + r16;
#pragma unroll
        for (int mt = 0; mt < 4; mt++) {
            uint2 pk = pack4bf(acc[mt][0], acc[mt][1], acc[mt][2], acc[mt][3]);
            *(uint2*)(sh + (size_t)cc * 64 + mt * 16 + quad * 4) = pk;
        }
    }
}

// ---------- combine: in-place scan over chunks; Sloc becomes ENTERING state ----------
__global__ void combine_kernel(unsigned short* __restrict__ Sloc, const float* __restrict__ dA, int layer) {
    int t = blockIdx.x * 256 + threadIdx.x;     // n(32) | b(8) | h(512)
    int n = t & 31;
    int b = (t >> 5) & 7;
    int h = t >> 8;
    int base = ((layer * N2 + n) * 2) * H + h;
    float dre = dA[base], dim = dA[base + H];
    float e = expf(dre * 64.f);
    float Lr = e * cosf(dim * 64.f), Li = e * sinf(dim * 64.f);
    unsigned int* p = (unsigned int*)Sloc + ((size_t)h * NCC + b * CPB) * 32 + n;
    float sr = 0.f, si = 0.f;
    for (int c = 0; c < CPB; c++) {
        unsigned int v = p[(size_t)c * 32];
        float pr = bf2f(v & 0xffff), pi = bf2f(v >> 16);
        p[(size_t)c * 32] = (unsigned)f2bf(sr) | ((unsigned)f2bf(si) << 16);
        float nr = fmaf(Lr, sr, fmaf(-Li, si, pr));
        float ni = fmaf(Lr, si, fmaf(Li, sr, pi));
        sr = nr; si = ni;
    }
}

// ---------- conv: Toeplitz GEMM + state-correction GEMM + D*u + gelu -> y_t ----------
__global__ __launch_bounds__(256) void conv_kernel(const unsigned short* __restrict__ ut,
                                                   const unsigned short* __restrict__ kmat,
                                                   const unsigned short* __restrict__ Vl,
                                                   const unsigned short* __restrict__ Sent,
                                                   const float* __restrict__ Dp,
                                                   unsigned short* __restrict__ yt, int layer) {
    __shared__ unsigned short T[64][72];
    int h = blockIdx.x, half = blockIdx.y;
    int t = threadIdx.x;
    const unsigned short* km = kmat + ((size_t)layer * H + h) * 64;
    {   // build lower-triangular Toeplitz T[l][j] = k[l-j]
        int l = t >> 2, j0 = (t & 3) * 16;
#pragma unroll
        for (int g = 0; g < 2; g++) {
            short8 v;
#pragma unroll
            for (int e = 0; e < 8; e++) {
                int j = j0 + g * 8 + e;
                v[e] = (j <= l) ? (short)km[l - j] : (short)0;
            }
            *reinterpret_cast<short8*>(&T[l][j0 + g * 8]) = v;
        }
    }
    __syncthreads();
    int wave = t >> 6, lane = t & 63;
    int r16 = lane & 15, quad = lane >> 4;
    const unsigned short* uh = ut + (size_t)h * BT;
    const unsigned short* vh = Vl + (size_t)h * 64 * 64;
    const unsigned short* eh = Sent + (size_t)h * NCC * 64;
    unsigned short* yh = yt + (size_t)h * BT;
    float Dh = Dp[layer * H + h];
    for (int nt = 0; nt < 4; nt++) {
        int cc0 = half * 256 + wave * 64 + nt * 16;
        float4v acc[4] = {};
#pragma unroll
        for (int k0 = 0; k0 < 64; k0 += 32) {    // Toeplitz part
            short8 bf = *reinterpret_cast<const short8*>(uh + (size_t)(cc0 + r16) * 64 + k0 + quad * 8);
#pragma unroll
            for (int mt = 0; mt < 4; mt++) {
                short8 af = *reinterpret_cast<const short8*>(&T[mt * 16 + r16][k0 + quad * 8]);
                acc[mt] = __builtin_amdgcn_mfma_f32_16x16x32_bf16(af, bf, acc[mt], 0, 0, 0);
            }
        }
#pragma unroll
        for (int k0 = 0; k0 < 64; k0 += 32) {    // entering-state correction
            short8 bf = *reinterpret_cast<const short8*>(eh + (size_t)(cc0 + r16) * 64 + k0 + quad * 8);
#pragma unroll
            for (int mt = 0; mt < 4; mt++) {
                short8 af = *reinterpret_cast<const short8*>(vh + (mt * 16 + r16) * 64 + k0 + quad * 8);
                acc[mt] = __builtin_amdgcn_mfma_f32_16x16x32_bf16(af, bf, acc[mt], 0, 0, 0);
            }
        }
        int cc = cc0 + r16;
#pragma unroll
        for (int mt = 0; mt < 4; mt++) {
            size_t p = (size_t)cc * 64 + mt * 16 + quad * 4;
            ushort4 uu = *(const ushort4*)(uh + p);
            float o[4];
#pragma unroll
            for (int r = 0; r < 4; r++) {
                float y = acc[mt][r] + Dh * bf2f(((const unsigned short*)&uu)[r]);
                o[r] = 0.5f * y * (1.0f + erff(y * 0.70710678118654752f));
            }
            *(uint2*)(yh + p) = pack4bf(o[0], o[1], o[2], o[3]);
        }
    }
}

// ---------- transpose y_t (H,BT bf16) -> ybf (BT,H bf16) ----------
__global__ __launch_bounds__(256) void transpose2_kernel(const unsigned short* __restrict__ yt,
                                                         unsigned short* __restrict__ yb) {
    __shared__ unsigned short tile[64][72];
    int bx = blockIdx.x;
    int pt = bx & 511, ht = bx >> 9;
    int p0 = pt * 64, h0 = ht * 64;
    int t = threadIdx.x;
    int jr = t & 7, ib = t >> 3;
#pragma unroll
    for (int pass = 0; pass < 2; pass++) {
        int i = ib + pass * 32;
        short8 v = *reinterpret_cast<const short8*>(yt + (size_t)(h0 + i) * BT + p0 + jr * 8);
#pragma unroll
        for (int e = 0; e < 8; e++) tile[i][jr * 8 + e] = (unsigned short)v[e];
    }
    __syncthreads();
    int pp = t >> 2, hg = t & 3;
    short8 o0, o1;
#pragma unroll
    for (int r = 0; r < 8; r++) o0[r] = (short)tile[hg * 16 + r][pp];
#pragma unroll
    for (int r = 0; r < 8; r++) o1[r] = (short)tile[hg * 16 + 8 + r][pp];
    unsigned short* dst = yb + (size_t)(p0 + pp) * H + h0 + hg * 16;
    *reinterpret_cast<short8*>(dst) = o0;
    *reinterpret_cast<short8*>(dst + 8) = o1;
}

// ---------- fused 1x1 conv (LDS-tiled bf16 MFMA) + bias + GLU -> yo bf16 ----------
__global__ __launch_bounds__(256) void gemm_glu_kernel(const unsigned short* __restrict__ ybf,
                                                       const unsigned short* __restrict__ Wbf,
                                                       const float* __restrict__ bias,
                                                       unsigned short* __restrict__ yo, int layer) {
    __shared__ unsigned short As[128 * 32];
    __shared__ unsigned short Bs[128 * 32];
    int tid = threadIdx.x;
    int wave = tid >> 6, lane = tid & 63;
    int wr = wave >> 1, wc = wave & 1;
    int r16 = lane & 15, quad = lane >> 4;
    int m0 = blockIdx.x * 128;
    int o0 = blockIdx.y * 64;
    const unsigned short* Wl = Wbf + (size_t)layer * 2 * H * H;

    int srow = lane >> 2;
    int scol = (lane & 3) * 8;
    const unsigned short* aSrc0 = ybf + ((size_t)(m0 + wave * 16 + srow)) * H + scol;
    const unsigned short* aSrc1 = aSrc0 + (size_t)64 * H;
    const unsigned short* bSrcA = Wl + ((size_t)(o0 + wave * 16 + srow)) * H + scol;
    const unsigned short* bSrcG = bSrcA + (size_t)512 * H;
    unsigned short* aDst0 = As + (wave * 16) * 32;
    unsigned short* aDst1 = As + (64 + wave * 16) * 32;
    unsigned short* bDstA = Bs + (wave * 16) * 32;
    unsigned short* bDstG = Bs + (64 + wave * 16) * 32;

    float4v acc_a[4][2] = {}, acc_g[4][2] = {};

    for (int k0 = 0; k0 < H; k0 += 32) {
        __syncthreads();
        async_copy16(aSrc0, aDst0);
        async_copy16(aSrc1, aDst1);
        async_copy16(bSrcA, bDstA);
        async_copy16(bSrcG, bDstG);
        aSrc0 += 32; aSrc1 += 32; bSrcA += 32; bSrcG += 32;
        __syncthreads();

        short8 af[4], ba[2], bg[2];
#pragma unroll
        for (int mi = 0; mi < 4; mi++)
            af[mi] = *reinterpret_cast<const short8*>(As + (wr * 64 + mi * 16 + r16) * 32 + quad * 8);
#pragma unroll
        for (int ni = 0; ni < 2; ni++) {
            ba[ni] = *reinterpret_cast<const short8*>(Bs + (wc * 32 + ni * 16 + r16) * 32 + quad * 8);
            bg[ni] = *reinterpret_cast<const short8*>(Bs + (64 + wc * 32 + ni * 16 + r16) * 32 + quad * 8);
        }
#pragma unroll
        for (int mi = 0; mi < 4; mi++)
#pragma unroll
            for (int ni = 0; ni < 2; ni++) {
                acc_a[mi][ni] = __builtin_amdgcn_mfma_f32_16x16x32_bf16(af[mi], ba[ni], acc_a[mi][ni], 0, 0, 0);
                acc_g[mi][ni] = __builtin_amdgcn_mfma_f32_16x16x32_bf16(af[mi], bg[ni], acc_g[mi][ni], 0, 0, 0);
            }
    }

    const float* bl = bias + layer * 2 * H;
#pragma unroll
    for (int ni = 0; ni < 2; ni++) {
        int o = o0 + wc * 32 + ni * 16 + r16;
        float ba_ = bl[o], bg_ = bl[H + o];
#pragma unroll
        for (int mi = 0; mi < 4; mi++)
#pragma unroll
            for (int r = 0; r < 4; r++) {
                int l = m0 + wr * 64 + mi * 16 + quad * 4 + r;
                float av = acc_a[mi][ni][r] + ba_;
                float gv = acc_g[mi][ni][r] + bg_;
                yo[(size_t)l * H + o] = f2bf(av * (1.0f / (1.0f + expf(-gv))));
            }
    }
}

// ---------- residual + LayerNorm ----------
__global__ __launch_bounds__(256) void ln_kernel(const unsigned short* __restrict__ yo,
                                                 const float* __restrict__ xin,
                                                 const float* __restrict__ gamma, const float* __restrict__ beta,
                                                 float* __restrict__ xout, int layer) {
    int wave = threadIdx.x >> 6, lane = threadIdx.x & 63;
    size_t row = (size_t)blockIdx.x * 4 + wave;
    const unsigned short* yp = yo + row * H + lane * 8;
    const float* xp = xin + row * H + lane * 8;
    short8 yv = *reinterpret_cast<const short8*>(yp);
    float4 x0 = *(const float4*)(xp);
    float4 x1 = *(const float4*)(xp + 4);
    float v[8];
    v[0] = bf2f((unsigned short)yv[0]) + x0.x; v[1] = bf2f((unsigned short)yv[1]) + x0.y;
    v[2] = bf2f((unsigned short)yv[2]) + x0.z; v[3] = bf2f((unsigned short)yv[3]) + x0.w;
    v[4] = bf2f((unsigned short)yv[4]) + x1.x; v[5] = bf2f((unsigned short)yv[5]) + x1.y;
    v[6] = bf2f((unsigned short)yv[6]) + x1.z; v[7] = bf2f((unsigned short)yv[7]) + x1.w;
    float s = 0.f, s2 = 0.f;
#pragma unroll
    for (int i = 0; i < 8; i++) { s += v[i]; s2 = fmaf(v[i], v[i], s2); }
#pragma unroll
    for (int off = 32; off; off >>= 1) {
        s += __shfl_xor(s, off);
        s2 += __shfl_xor(s2, off);
    }
    float mu = s * (1.0f / H);
    float var = s2 * (1.0f / H) - mu * mu;
    float inv = rsqrtf(var + 1e-5f);
    const float* gl = gamma + layer * H + lane * 8;
    const float* bl = beta + layer * H + lane * 8;
    float* op = xout + row * H + lane * 8;
#pragma unroll
    for (int i = 0; i < 8; i++)
        op[i] = (v[i] - mu) * inv * gl[i] + bl[i];
}

extern "C" void kernel_launch(void* const* d_in, const int* in_sizes, int n_in,
                              void* d_out, int out_size, void* d_ws, size_t ws_size,
                              hipStream_t stream) {
    const float* x          = (const float*)d_in[0];
    const float* log_dt     = (const float*)d_in[1];
    const float* A_imag     = (const float*)d_in[2];
    const float* log_A_real = (const float*)d_in[3];
    const float* C          = (const float*)d_in[4];
    const float* D          = (const float*)d_in[5];
    const float* W          = (const float*)d_in[6];
    const float* bias       = (const float*)d_in[7];
    const float* gamma      = (const float*)d_in[8];
    const float* beta       = (const float*)d_in[9];

    char* ws = (char*)d_ws;
    float*          xA   = (float*)(ws + 0);
    unsigned short* Sloc = (unsigned short*)(ws + 67108864);
    unsigned short* u_t  = (unsigned short*)(ws + 100663296);
    unsigned short* ybf  = (unsigned short*)(ws + 100663296);   // overlay: after conv, u_t dead
    unsigned short* y_t  = (unsigned short*)(ws + 134217728);
    unsigned short* yo   = (unsigned short*)(ws + 134217728);   // overlay: after transpose2, y_t dead
    unsigned short* Wbf  = (unsigned short*)(ws + 167772160);
    unsigned short* WV   = (unsigned short*)(ws + 171966464);   // Wstate then V per layer
    unsigned short* kmat = (unsigned short*)(ws + 176160768);
    float*          dA   = (float*)(ws + 176422912);
    float*          Ct   = (float*)(ws + 176947200);
    float* xout_final    = (float*)d_out;

    wconv_kernel<<<NL * 2 * H * H / 256, 256, 0, stream>>>(W, Wbf);
    params_kernel<<<NL * N2 * H / 256, 256, 0, stream>>>(log_dt, A_imag, log_A_real, C, dA, Ct);
    kergen_k_kernel<<<NL * H * 64 / 256, 256, 0, stream>>>(dA, Ct, kmat);

    const float* xi = x;
    float* bufs[NL] = { xA, xout_final, xA, xout_final };
    for (int layer = 0; layer < NL; ++layer) {
        float* xo = bufs[layer];
        transpose1_kernel<<<4096, 256, 0, stream>>>(xi, u_t);
        kergenW_kernel<<<H * 64 * 64 / 256, 256, 0, stream>>>(dA, WV, layer);
        states_kernel<<<H, 256, 0, stream>>>(u_t, WV, Sloc);
        combine_kernel<<<H * Bsz * N2 / 256, 256, 0, stream>>>(Sloc, dA, layer);
        kergenV_kernel<<<H * 64 * 64 / 256, 256, 0, stream>>>(dA, Ct, WV, layer);
        conv_kernel<<<dim3(H, 2), 256, 0, stream>>>(u_t, kmat, WV, Sloc, D, y_t, layer);
        transpose2_kernel<<<4096, 256, 0, stream>>>(y_t, ybf);
        gemm_glu_kernel<<<dim3(BT / 128, H / 64), 256, 0, stream>>>(ybf, Wbf, bias, yo, layer);
        ln_kernel<<<BT / 4, 256, 0, stream>>>(yo, xi, gamma, beta, xo, layer);
        xi = xo;
    }
}

// Round 4
// 863.405 us; speedup vs baseline: 1.9555x; 1.0690x over previous
//
#include <hip/hip_runtime.h>
#include <hip/hip_bf16.h>
#include <math.h>

#define H 512
#define NL 4
#define N2 32
#define Bsz 8
#define Lseq 4096
#define BT (Bsz*Lseq)        // 32768 total positions
#define LC2 64               // chunk length
#define NCC (BT/LC2)         // 512 chunks total
#define CPB (Lseq/LC2)       // 64 chunks per batch element

typedef __attribute__((ext_vector_type(8))) short short8;   // 8 bf16
typedef __attribute__((ext_vector_type(4))) float float4v;

// ---------------- ws layout (bytes) ----------------
// 0         : xR   (bf16 BT*H residual)        33554432
// 67108864  : Sloc (bf16 H*NCC*64)             33554432
// 100663296 : u_t  (bf16 H*BT) / ybf overlay   33554432
// 134217728 : y_t  (bf16 H*BT) / yo overlay    33554432
// 167772160 : Wbf  (bf16 NL*2H*H)               4194304
// 171966464 : WV   (bf16 H*64*64, Wstate->V)    4194304
// 176160768 : kmat (bf16 NL*H*64)                262144
// 176422912 : dA   (fp32 NL*N2*2*H)              524288
// 176947200 : Ct   (fp32 NL*N2*2*H)              524288

__device__ __forceinline__ float bf2f(unsigned short u) {
    union { unsigned int i; float f; } x; x.i = ((unsigned int)u) << 16; return x.f;
}
__device__ __forceinline__ unsigned short f2bf(float f) {
    union { float f; unsigned int i; } x; x.f = f;
    unsigned int u = x.i + 0x7fff + ((x.i >> 16) & 1);
    return (unsigned short)(u >> 16);
}
__device__ __forceinline__ uint2 pack4bf(float a, float b, float c, float d) {
    uint2 r;
    r.x = (unsigned)f2bf(a) | ((unsigned)f2bf(b) << 16);
    r.y = (unsigned)f2bf(c) | ((unsigned)f2bf(d) << 16);
    return r;
}
__device__ __forceinline__ void async_copy16(const void* g, void* l) {
    __builtin_amdgcn_global_load_lds(
        (const __attribute__((address_space(1))) void*)g,
        (__attribute__((address_space(3))) void*)l, 16, 0, 0);
}

// ---------- convert W to bf16 ----------
__global__ void wconv_kernel(const float* __restrict__ W, unsigned short* __restrict__ Wbf) {
    int tid = blockIdx.x * 256 + threadIdx.x;
    Wbf[tid] = f2bf(W[tid]);
}

// ---------- per-(layer,n,h): dA = log(lambda), Ct = 2C(lambda-1)/A ----------
__global__ void params_kernel(const float* __restrict__ log_dt, const float* __restrict__ A_imag,
                              const float* __restrict__ log_A_real, const float* __restrict__ Cin,
                              float* __restrict__ dA, float* __restrict__ Ct) {
    int tid = blockIdx.x * 256 + threadIdx.x;   // ((layer*N2+n)*H + h)
    int h = tid % H;
    int n = (tid / H) % N2;
    int layer = tid / (H * N2);
    float dt = expf(log_dt[layer * H + h]);
    int pidx = (layer * H + h) * N2 + n;
    float Are = -expf(log_A_real[pidx]);
    float Aim = A_imag[pidx];
    float dre = Are * dt, dim = Aim * dt;
    float er = expf(dre);
    float lre = er * cosf(dim), lim = er * sinf(dim);
    float nre = lre - 1.0f, nim = lim;
    float inv = 1.0f / (Are * Are + Aim * Aim);
    float tre = (nre * Are + nim * Aim) * inv;
    float tim = (nim * Are - nre * Aim) * inv;
    float Ccre = Cin[pidx * 2], Ccim = Cin[pidx * 2 + 1];
    int oidx = ((layer * N2 + n) * 2) * H + h;
    dA[oidx] = dre;  dA[oidx + H] = dim;
    Ct[oidx] = 2.0f * (Ccre * tre - Ccim * tim);
    Ct[oidx + H] = 2.0f * (Ccre * tim + Ccim * tre);
}

// ---------- kernels k[d] = Re sum_n Ct_n lambda_n^d, all layers ----------
__global__ void kergen_k_kernel(const float* __restrict__ dA, const float* __restrict__ Ct,
                                unsigned short* __restrict__ kmat) {
    int t = blockIdx.x * 256 + threadIdx.x;     // (layer*H + h)*64 + d
    int d = t & 63;
    int h = (t >> 6) & (H - 1);
    int layer = t >> 15;
    float fd = (float)d;
    float sum = 0.f;
    for (int n = 0; n < N2; n++) {
        int base = ((layer * N2 + n) * 2) * H + h;
        float dre = dA[base], dim = dA[base + H];
        float Ctr = Ct[base], Cti = Ct[base + H];
        float e = expf(dre * fd);
        sum += Ctr * e * cosf(dim * fd) - Cti * e * sinf(dim * fd);
    }
    kmat[t] = f2bf(sum);
}

// ---------- Wstate[h][r][j]: r=2n -> Re(l^(63-j)), r=2n+1 -> Im ----------
__global__ void kergenW_kernel(const float* __restrict__ dA, unsigned short* __restrict__ Wst, int layer) {
    int t = blockIdx.x * 256 + threadIdx.x;     // (h*64 + r)*64 + j
    int j = t & 63;
    int r = (t >> 6) & 63;
    int h = t >> 12;
    int n = r >> 1;
    int base = ((layer * N2 + n) * 2) * H + h;
    float dre = dA[base], dim = dA[base + H];
    float p = (float)(63 - j);
    float e = expf(dre * p);
    Wst[t] = f2bf((r & 1) ? e * sinf(dim * p) : e * cosf(dim * p));
}

// ---------- V[h][l][c2]: c2=2n -> Re(Ct l^(l+1)), c2=2n+1 -> -Im ----------
__global__ void kergenV_kernel(const float* __restrict__ dA, const float* __restrict__ Ct,
                               unsigned short* __restrict__ Vl, int layer) {
    int t = blockIdx.x * 256 + threadIdx.x;     // (h*64 + l)*64 + c2
    int c2 = t & 63;
    int l = (t >> 6) & 63;
    int h = t >> 12;
    int n = c2 >> 1;
    int base = ((layer * N2 + n) * 2) * H + h;
    float dre = dA[base], dim = dA[base + H];
    float Ctr = Ct[base], Cti = Ct[base + H];
    float q = (float)(l + 1);
    float e = expf(dre * q);
    float ar = e * cosf(dim * q), ai = e * sinf(dim * q);
    float vre = Ctr * ar - Cti * ai;
    float vim = Ctr * ai + Cti * ar;
    Vl[t] = f2bf((c2 & 1) ? -vim : vre);
}

// ---------- transpose x fp32 (BT,H) -> u_t bf16 (H,BT)  [layer 0] ----------
__global__ __launch_bounds__(256) void t1_f32_kernel(const float* __restrict__ xi,
                                                     unsigned short* __restrict__ ut) {
    __shared__ float tile[64][68];
    int bx = blockIdx.x;
    int pt = bx & 511, ht = bx >> 9;
    int p0 = pt * 64, h0 = ht * 64;
    int t = threadIdx.x;
    int jr = t & 15, ib = t >> 4;
#pragma unroll
    for (int pass = 0; pass < 4; pass++) {
        int i = ib + pass * 16;
        float4 v = *(const float4*)(xi + (size_t)(p0 + i) * H + h0 + jr * 4);
        tile[i][jr * 4 + 0] = v.x; tile[i][jr * 4 + 1] = v.y;
        tile[i][jr * 4 + 2] = v.z; tile[i][jr * 4 + 3] = v.w;
    }
    __syncthreads();
#pragma unroll
    for (int pass = 0; pass < 4; pass++) {
        int i2 = ib + pass * 16;
        int j2 = jr * 4;
        uint2 pk = pack4bf(tile[j2][i2], tile[j2 + 1][i2], tile[j2 + 2][i2], tile[j2 + 3][i2]);
        *(uint2*)(ut + (size_t)(h0 + i2) * BT + p0 + j2) = pk;
    }
}

// ---------- transpose xR bf16 (BT,H) -> u_t bf16 (H,BT)  [layers >=1] ----------
__global__ __launch_bounds__(256) void t1_bf16_kernel(const unsigned short* __restrict__ xi,
                                                      unsigned short* __restrict__ ut) {
    __shared__ unsigned short tile[64][72];
    int bx = blockIdx.x;
    int pt = bx & 511, ht = bx >> 9;
    int p0 = pt * 64, h0 = ht * 64;
    int t = threadIdx.x;
    int jr = t & 7, ib = t >> 3;
#pragma unroll
    for (int pass = 0; pass < 2; pass++) {
        int i = ib + pass * 32;   // bt-row within tile
        short8 v = *reinterpret_cast<const short8*>(xi + (size_t)(p0 + i) * H + h0 + jr * 8);
#pragma unroll
        for (int e = 0; e < 8; e++) tile[i][jr * 8 + e] = (unsigned short)v[e];
    }
    __syncthreads();
    int hr = t >> 2, bg = t & 3;
    short8 o0, o1;
#pragma unroll
    for (int r = 0; r < 8; r++) o0[r] = (short)tile[bg * 16 + r][hr];
#pragma unroll
    for (int r = 0; r < 8; r++) o1[r] = (short)tile[bg * 16 + 8 + r][hr];
    unsigned short* dst = ut + (size_t)(h0 + hr) * BT + p0 + bg * 16;
    *reinterpret_cast<short8*>(dst) = o0;
    *reinterpret_cast<short8*>(dst + 8) = o1;
}

// ---------- local chunk states: Sloc[h][cc][r] = sum_j Wst[r][j] u[cc*64+j] ----------
__global__ __launch_bounds__(256) void states_kernel(const unsigned short* __restrict__ ut,
                                                     const unsigned short* __restrict__ Wst,
                                                     unsigned short* __restrict__ Sloc) {
    int h = blockIdx.x;
    int wave = threadIdx.x >> 6, lane = threadIdx.x & 63;
    int r16 = lane & 15, quad = lane >> 4;
    const unsigned short* uh = ut + (size_t)h * BT;
    const unsigned short* wh = Wst + (size_t)h * 64 * 64;
    unsigned short* sh = Sloc + (size_t)h * NCC * 64;
    for (int nt = 0; nt < 8; nt++) {
        int cc0 = wave * 128 + nt * 16;
        float4v acc[4] = {};
#pragma unroll
        for (int k0 = 0; k0 < 64; k0 += 32) {
            short8 bf = *reinterpret_cast<const short8*>(uh + (size_t)(cc0 + r16) * 64 + k0 + quad * 8);
#pragma unroll
            for (int mt = 0; mt < 4; mt++) {
                short8 af = *reinterpret_cast<const short8*>(wh + (mt * 16 + r16) * 64 + k0 + quad * 8);
                acc[mt] = __builtin_amdgcn_mfma_f32_16x16x32_bf16(af, bf, acc[mt], 0, 0, 0);
            }
        }
        int cc = cc0 + r16;
#pragma unroll
        for (int mt = 0; mt < 4; mt++) {
            uint2 pk = pack4bf(acc[mt][0], acc[mt][1], acc[mt][2], acc[mt][3]);
            *(uint2*)(sh + (size_t)cc * 64 + mt * 16 + quad * 4) = pk;
        }
    }
}

// ---------- combine: in-place scan over chunks; Sloc becomes ENTERING state ----------
__global__ void combine_kernel(unsigned short* __restrict__ Sloc, const float* __restrict__ dA, int layer) {
    int t = blockIdx.x * 256 + threadIdx.x;     // n(32) | b(8) | h(512)
    int n = t & 31;
    int b = (t >> 5) & 7;
    int h = t >> 8;
    int base = ((layer * N2 + n) * 2) * H + h;
    float dre = dA[base], dim = dA[base + H];
    float e = expf(dre * 64.f);
    float Lr = e * cosf(dim * 64.f), Li = e * sinf(dim * 64.f);
    unsigned int* p = (unsigned int*)Sloc + ((size_t)h * NCC + b * CPB) * 32 + n;
    float sr = 0.f, si = 0.f;
    for (int c = 0; c < CPB; c++) {
        unsigned int v = p[(size_t)c * 32];
        float pr = bf2f(v & 0xffff), pi = bf2f(v >> 16);
        p[(size_t)c * 32] = (unsigned)f2bf(sr) | ((unsigned)f2bf(si) << 16);
        float nr = fmaf(Lr, sr, fmaf(-Li, si, pr));
        float ni = fmaf(Lr, si, fmaf(Li, sr, pi));
        sr = nr; si = ni;
    }
}

// ---------- conv: Toeplitz GEMM + state-correction GEMM + D*u + gelu -> y_t ----------
__global__ __launch_bounds__(256) void conv_kernel(const unsigned short* __restrict__ ut,
                                                   const unsigned short* __restrict__ kmat,
                                                   const unsigned short* __restrict__ Vl,
                                                   const unsigned short* __restrict__ Sent,
                                                   const float* __restrict__ Dp,
                                                   unsigned short* __restrict__ yt, int layer) {
    __shared__ unsigned short T[64][72];
    int h = blockIdx.x, half = blockIdx.y;
    int t = threadIdx.x;
    const unsigned short* km = kmat + ((size_t)layer * H + h) * 64;
    {   // build lower-triangular Toeplitz T[l][j] = k[l-j]
        int l = t >> 2, j0 = (t & 3) * 16;
#pragma unroll
        for (int g = 0; g < 2; g++) {
            short8 v;
#pragma unroll
            for (int e = 0; e < 8; e++) {
                int j = j0 + g * 8 + e;
                v[e] = (j <= l) ? (short)km[l - j] : (short)0;
            }
            *reinterpret_cast<short8*>(&T[l][j0 + g * 8]) = v;
        }
    }
    __syncthreads();
    int wave = t >> 6, lane = t & 63;
    int r16 = lane & 15, quad = lane >> 4;
    const unsigned short* uh = ut + (size_t)h * BT;
    const unsigned short* vh = Vl + (size_t)h * 64 * 64;
    const unsigned short* eh = Sent + (size_t)h * NCC * 64;
    unsigned short* yh = yt + (size_t)h * BT;
    float Dh = Dp[layer * H + h];
    for (int nt = 0; nt < 4; nt++) {
        int cc0 = half * 256 + wave * 64 + nt * 16;
        float4v acc[4] = {};
#pragma unroll
        for (int k0 = 0; k0 < 64; k0 += 32) {    // Toeplitz part
            short8 bf = *reinterpret_cast<const short8*>(uh + (size_t)(cc0 + r16) * 64 + k0 + quad * 8);
#pragma unroll
            for (int mt = 0; mt < 4; mt++) {
                short8 af = *reinterpret_cast<const short8*>(&T[mt * 16 + r16][k0 + quad * 8]);
                acc[mt] = __builtin_amdgcn_mfma_f32_16x16x32_bf16(af, bf, acc[mt], 0, 0, 0);
            }
        }
#pragma unroll
        for (int k0 = 0; k0 < 64; k0 += 32) {    // entering-state correction
            short8 bf = *reinterpret_cast<const short8*>(eh + (size_t)(cc0 + r16) * 64 + k0 + quad * 8);
#pragma unroll
            for (int mt = 0; mt < 4; mt++) {
                short8 af = *reinterpret_cast<const short8*>(vh + (mt * 16 + r16) * 64 + k0 + quad * 8);
                acc[mt] = __builtin_amdgcn_mfma_f32_16x16x32_bf16(af, bf, acc[mt], 0, 0, 0);
            }
        }
        int cc = cc0 + r16;
#pragma unroll
        for (int mt = 0; mt < 4; mt++) {
            size_t p = (size_t)cc * 64 + mt * 16 + quad * 4;
            ushort4 uu = *(const ushort4*)(uh + p);
            float o[4];
#pragma unroll
            for (int r = 0; r < 4; r++) {
                float y = acc[mt][r] + Dh * bf2f(((const unsigned short*)&uu)[r]);
                o[r] = 0.5f * y * (1.0f + erff(y * 0.70710678118654752f));
            }
            *(uint2*)(yh + p) = pack4bf(o[0], o[1], o[2], o[3]);
        }
    }
}

// ---------- transpose y_t (H,BT bf16) -> ybf (BT,H bf16) ----------
__global__ __launch_bounds__(256) void transpose2_kernel(const unsigned short* __restrict__ yt,
                                                         unsigned short* __restrict__ yb) {
    __shared__ unsigned short tile[64][72];
    int bx = blockIdx.x;
    int pt = bx & 511, ht = bx >> 9;
    int p0 = pt * 64, h0 = ht * 64;
    int t = threadIdx.x;
    int jr = t & 7, ib = t >> 3;
#pragma unroll
    for (int pass = 0; pass < 2; pass++) {
        int i = ib + pass * 32;
        short8 v = *reinterpret_cast<const short8*>(yt + (size_t)(h0 + i) * BT + p0 + jr * 8);
#pragma unroll
        for (int e = 0; e < 8; e++) tile[i][jr * 8 + e] = (unsigned short)v[e];
    }
    __syncthreads();
    int pp = t >> 2, hg = t & 3;
    short8 o0, o1;
#pragma unroll
    for (int r = 0; r < 8; r++) o0[r] = (short)tile[hg * 16 + r][pp];
#pragma unroll
    for (int r = 0; r < 8; r++) o1[r] = (short)tile[hg * 16 + 8 + r][pp];
    unsigned short* dst = yb + (size_t)(p0 + pp) * H + h0 + hg * 16;
    *reinterpret_cast<short8*>(dst) = o0;
    *reinterpret_cast<short8*>(dst + 8) = o1;
}

// ---------- fused 1x1 conv (LDS-tiled, bank-conflict-free swizzle) + bias + GLU ----------
// LDS chunk (row r, c) holds global chunk (r, c ^ ((r>>1)&3)); reads use the inverse.
__global__ __launch_bounds__(256) void gemm_glu_kernel(const unsigned short* __restrict__ ybf,
                                                       const unsigned short* __restrict__ Wbf,
                                                       const float* __restrict__ bias,
                                                       unsigned short* __restrict__ yo, int layer) {
    __shared__ unsigned short As[128 * 32];
    __shared__ unsigned short Bs[128 * 32];
    int tid = threadIdx.x;
    int wave = tid >> 6, lane = tid & 63;
    int wr = wave >> 1, wc = wave & 1;
    int r16 = lane & 15, quad = lane >> 4;
    int m0 = blockIdx.x * 128;
    int o0 = blockIdx.y * 64;
    const unsigned short* Wl = Wbf + (size_t)layer * 2 * H * H;

    // staging: lane -> LDS row lane>>2, chunk lane&3; source col chunk is XOR-swizzled
    int srow = lane >> 2;
    int scol = ((lane & 3) ^ ((srow >> 1) & 3)) * 8;
    const unsigned short* aSrc0 = ybf + ((size_t)(m0 + wave * 16 + srow)) * H + scol;
    const unsigned short* aSrc1 = aSrc0 + (size_t)64 * H;
    const unsigned short* bSrcA = Wl + ((size_t)(o0 + wave * 16 + srow)) * H + scol;
    const unsigned short* bSrcG = bSrcA + (size_t)512 * H;
    unsigned short* aDst0 = As + (wave * 16) * 32;
    unsigned short* aDst1 = As + (64 + wave * 16) * 32;
    unsigned short* bDstA = Bs + (wave * 16) * 32;
    unsigned short* bDstG = Bs + (64 + wave * 16) * 32;

    int rcol = (quad ^ ((r16 >> 1) & 3)) * 8;   // swizzled fragment column

    float4v acc_a[4][2] = {}, acc_g[4][2] = {};

    for (int k0 = 0; k0 < H; k0 += 32) {
        __syncthreads();
        async_copy16(aSrc0, aDst0);
        async_copy16(aSrc1, aDst1);
        async_copy16(bSrcA, bDstA);
        async_copy16(bSrcG, bDstG);
        aSrc0 += 32; aSrc1 += 32; bSrcA += 32; bSrcG += 32;
        __syncthreads();

        short8 af[4], ba[2], bg[2];
#pragma unroll
        for (int mi = 0; mi < 4; mi++)
            af[mi] = *reinterpret_cast<const short8*>(As + (wr * 64 + mi * 16 + r16) * 32 + rcol);
#pragma unroll
        for (int ni = 0; ni < 2; ni++) {
            ba[ni] = *reinterpret_cast<const short8*>(Bs + (wc * 32 + ni * 16 + r16) * 32 + rcol);
            bg[ni] = *reinterpret_cast<const short8*>(Bs + (64 + wc * 32 + ni * 16 + r16) * 32 + rcol);
        }
#pragma unroll
        for (int mi = 0; mi < 4; mi++)
#pragma unroll
            for (int ni = 0; ni < 2; ni++) {
                acc_a[mi][ni] = __builtin_amdgcn_mfma_f32_16x16x32_bf16(af[mi], ba[ni], acc_a[mi][ni], 0, 0, 0);
                acc_g[mi][ni] = __builtin_amdgcn_mfma_f32_16x16x32_bf16(af[mi], bg[ni], acc_g[mi][ni], 0, 0, 0);
            }
    }

    const float* bl = bias + layer * 2 * H;
#pragma unroll
    for (int ni = 0; ni < 2; ni++) {
        int o = o0 + wc * 32 + ni * 16 + r16;
        float ba_ = bl[o], bg_ = bl[H + o];
#pragma unroll
        for (int mi = 0; mi < 4; mi++)
#pragma unroll
            for (int r = 0; r < 4; r++) {
                int l = m0 + wr * 64 + mi * 16 + quad * 4 + r;
                float av = acc_a[mi][ni][r] + ba_;
                float gv = acc_g[mi][ni][r] + bg_;
                yo[(size_t)l * H + o] = f2bf(av * (1.0f / (1.0f + expf(-gv))));
            }
    }
}

// ---------- residual + LayerNorm (bf16 residual stream; final layer fp32) ----------
__global__ __launch_bounds__(256) void ln_kernel(const unsigned short* __restrict__ yo,
                                                 const float* __restrict__ xf,
                                                 const unsigned short* __restrict__ xb,
                                                 const float* __restrict__ gamma, const float* __restrict__ beta,
                                                 float* __restrict__ of, unsigned short* __restrict__ ob,
                                                 int in_f32, int out_f32, int layer) {
    int wave = threadIdx.x >> 6, lane = threadIdx.x & 63;
    size_t row = (size_t)blockIdx.x * 4 + wave;
    const unsigned short* yp = yo + row * H + lane * 8;
    short8 yv = *reinterpret_cast<const short8*>(yp);
    float v[8];
    if (in_f32) {
        const float* xp = xf + row * H + lane * 8;
        float4 x0 = *(const float4*)(xp);
        float4 x1 = *(const float4*)(xp + 4);
        v[0] = bf2f((unsigned short)yv[0]) + x0.x; v[1] = bf2f((unsigned short)yv[1]) + x0.y;
        v[2] = bf2f((unsigned short)yv[2]) + x0.z; v[3] = bf2f((unsigned short)yv[3]) + x0.w;
        v[4] = bf2f((unsigned short)yv[4]) + x1.x; v[5] = bf2f((unsigned short)yv[5]) + x1.y;
        v[6] = bf2f((unsigned short)yv[6]) + x1.z; v[7] = bf2f((unsigned short)yv[7]) + x1.w;
    } else {
        const unsigned short* xp = xb + row * H + lane * 8;
        short8 xv = *reinterpret_cast<const short8*>(xp);
#pragma unroll
        for (int i = 0; i < 8; i++)
            v[i] = bf2f((unsigned short)yv[i]) + bf2f((unsigned short)xv[i]);
    }
    float s = 0.f, s2 = 0.f;
#pragma unroll
    for (int i = 0; i < 8; i++) { s += v[i]; s2 = fmaf(v[i], v[i], s2); }
#pragma unroll
    for (int off = 32; off; off >>= 1) {
        s += __shfl_xor(s, off);
        s2 += __shfl_xor(s2, off);
    }
    float mu = s * (1.0f / H);
    float var = s2 * (1.0f / H) - mu * mu;
    float inv = rsqrtf(var + 1e-5f);
    const float* gl = gamma + layer * H + lane * 8;
    const float* bl = beta + layer * H + lane * 8;
    float o[8];
#pragma unroll
    for (int i = 0; i < 8; i++)
        o[i] = (v[i] - mu) * inv * gl[i] + bl[i];
    if (out_f32) {
        float* op = of + row * H + lane * 8;
        *(float4*)(op) = make_float4(o[0], o[1], o[2], o[3]);
        *(float4*)(op + 4) = make_float4(o[4], o[5], o[6], o[7]);
    } else {
        unsigned short* op = ob + row * H + lane * 8;
        uint2 p0 = pack4bf(o[0], o[1], o[2], o[3]);
        uint2 p1 = pack4bf(o[4], o[5], o[6], o[7]);
        *(uint2*)(op) = p0;
        *(uint2*)(op + 4) = p1;
    }
}

extern "C" void kernel_launch(void* const* d_in, const int* in_sizes, int n_in,
                              void* d_out, int out_size, void* d_ws, size_t ws_size,
                              hipStream_t stream) {
    const float* x          = (const float*)d_in[0];
    const float* log_dt     = (const float*)d_in[1];
    const float* A_imag     = (const float*)d_in[2];
    const float* log_A_real = (const float*)d_in[3];
    const float* C          = (const float*)d_in[4];
    const float* D          = (const float*)d_in[5];
    const float* W          = (const float*)d_in[6];
    const float* bias       = (const float*)d_in[7];
    const float* gamma      = (const float*)d_in[8];
    const float* beta       = (const float*)d_in[9];

    char* ws = (char*)d_ws;
    unsigned short* xR   = (unsigned short*)(ws + 0);           // bf16 residual stream
    unsigned short* Sloc = (unsigned short*)(ws + 67108864);
    unsigned short* u_t  = (unsigned short*)(ws + 100663296);
    unsigned short* ybf  = (unsigned short*)(ws + 100663296);   // overlay: after conv, u_t dead
    unsigned short* y_t  = (unsigned short*)(ws + 134217728);
    unsigned short* yo   = (unsigned short*)(ws + 134217728);   // overlay: after transpose2, y_t dead
    unsigned short* Wbf  = (unsigned short*)(ws + 167772160);
    unsigned short* WV   = (unsigned short*)(ws + 171966464);   // Wstate then V per layer
    unsigned short* kmat = (unsigned short*)(ws + 176160768);
    float*          dA   = (float*)(ws + 176422912);
    float*          Ct   = (float*)(ws + 176947200);
    float* xout_final    = (float*)d_out;

    wconv_kernel<<<NL * 2 * H * H / 256, 256, 0, stream>>>(W, Wbf);
    params_kernel<<<NL * N2 * H / 256, 256, 0, stream>>>(log_dt, A_imag, log_A_real, C, dA, Ct);
    kergen_k_kernel<<<NL * H * 64 / 256, 256, 0, stream>>>(dA, Ct, kmat);

    for (int layer = 0; layer < NL; ++layer) {
        if (layer == 0)
            t1_f32_kernel<<<4096, 256, 0, stream>>>(x, u_t);
        else
            t1_bf16_kernel<<<4096, 256, 0, stream>>>(xR, u_t);
        kergenW_kernel<<<H * 64 * 64 / 256, 256, 0, stream>>>(dA, WV, layer);
        states_kernel<<<H, 256, 0, stream>>>(u_t, WV, Sloc);
        combine_kernel<<<H * Bsz * N2 / 256, 256, 0, stream>>>(Sloc, dA, layer);
        kergenV_kernel<<<H * 64 * 64 / 256, 256, 0, stream>>>(dA, Ct, WV, layer);
        conv_kernel<<<dim3(H, 2), 256, 0, stream>>>(u_t, kmat, WV, Sloc, D, y_t, layer);
        transpose2_kernel<<<4096, 256, 0, stream>>>(y_t, ybf);
        gemm_glu_kernel<<<dim3(BT / 128, H / 64), 256, 0, stream>>>(ybf, Wbf, bias, yo, layer);
        int in_f32 = (layer == 0), out_f32 = (layer == NL - 1);
        ln_kernel<<<BT / 4, 256, 0, stream>>>(yo, x, xR, gamma, beta,
                                              xout_final, xR, in_f32, out_f32, layer);
    }
}